// Round 4
// baseline (28.679 us; speedup 1.0000x reference)
//
#include <hip/hip_runtime.h>
#include <hip/hip_bf16.h>
#include <math.h>

#define Bn   16
#define T1n  256
#define T2n  256
#define Dn   256
#define MPn  32

typedef __attribute__((ext_vector_type(8))) short short8;
typedef __attribute__((ext_vector_type(4))) float f32x4;

typedef const __attribute__((address_space(1))) void* gp_t;
typedef __attribute__((address_space(3))) void* lp_t;

__device__ __forceinline__ void gl_lds16(const void* g, void* l) {
  // async global->LDS, 16B/lane; LDS dest = wave-uniform base + lane*16
  __builtin_amdgcn_global_load_lds((gp_t)g, (lp_t)l, 16, 0, 0);
}

__device__ inline short f2b(float f) {
  __hip_bfloat16 h = __float2bfloat16(f);
  return __builtin_bit_cast(short, h);
}
__device__ inline float b2f(short s) {
  unsigned int u = ((unsigned int)(unsigned short)s) << 16;
  return __builtin_bit_cast(float, u);
}
__device__ inline float max4(f32x4 a) {
  return fmaxf(fmaxf(a.x, a.y), fmaxf(a.z, a.w));
}

// swizzled 16B-chunk index within a [rows][256 d] bf16 tile.
// XOR of row&7 spreads stride-512B column reads across 8 16B slots.
// Involution: gl_lds source pre-swizzle uses the same XOR (linear LDS dest).
__device__ inline int swz_chunk(int row, int d8) {
  return row * 32 + (d8 ^ (row & 7));
}

// ---------------- pre-pass: f32 -> bf16 for lt and rt ----------------
__global__ __launch_bounds__(256, 8)
void cvt_bf16_kernel(const float* __restrict__ lt, const float* __restrict__ rt,
                     short* __restrict__ olt, short* __restrict__ ort) {
  int blk = blockIdx.x;
  const float* src;
  short* dst;
  int t;
  if (blk < 512) { src = lt; dst = olt; t = blk * 256 + threadIdx.x; }
  else           { src = rt; dst = ort; t = (blk - 512) * 256 + threadIdx.x; }
  const f32x4* s = reinterpret_cast<const f32x4*>(src + (size_t)t * 8);
  f32x4 f0 = s[0], f1 = s[1];
  short8 v;
  v[0] = f2b(f0.x); v[1] = f2b(f0.y); v[2] = f2b(f0.z); v[3] = f2b(f0.w);
  v[4] = f2b(f1.x); v[5] = f2b(f1.y); v[6] = f2b(f1.z); v[7] = f2b(f1.w);
  *reinterpret_cast<short8*>(dst + (size_t)t * 8) = v;
}

// -------- main: 1024 blocks = b(16) x jblk(8, 32j) x mg(8, 4m); 4 waves --------
__global__ __launch_bounds__(256, 3)
void mp_match_kernel(const short* __restrict__ ltb,
                     const short* __restrict__ rtb,
                     const float* __restrict__ kern,
                     float* __restrict__ out) {
  __shared__ short lds_rt[32 * 256];        // 16 KB
  __shared__ short lds_lt[2][32 * 256];     // 32 KB dbuf   -> 48 KB total, 3 blk/CU

  const int bid = blockIdx.x;
  const int xcd = bid & 7;                  // b in {xcd, 8+xcd} -> L2 locality
  const int idx = bid >> 3;                 // 0..127
  const int b   = ((idx >> 6) << 3) | xcd;
  const int rem = idx & 63;
  const int jblk = rem & 7;
  const int mg   = rem >> 3;
  const int j0   = jblk * 32;

  const int tid  = threadIdx.x;             // 0..255
  const int lane = tid & 63;
  const int w    = tid >> 6;                // wave -> its own m
  const int m    = mg * 4 + w;
  const int bl   = lane & 15;
  const int hl   = lane >> 4;

  // staging: [32 row][256 d] bf16 tile = 1024 16B chunks; 4 gl_lds/thread.
  // linear LDS dest chunk = cidx; global source pre-swizzled (involution).
  int soff[4];
  #pragma unroll
  for (int it = 0; it < 4; ++it) {
    int cidx = it * 256 + tid;
    int row = cidx >> 5, slot = cidx & 31;
    soff[it] = row * 256 + (slot ^ (row & 7)) * 8;
  }
  const int wub = (tid & ~63) * 8;          // wave-uniform part of dest (shorts)

  // ---- stage rt tile ----
  const short* rbase = rtb + ((size_t)b * T2n + j0) * Dn;
  #pragma unroll
  for (int it = 0; it < 4; ++it)
    gl_lds16(rbase + soff[it], &lds_rt[it * 256 * 8 + wub]);
  asm volatile("s_waitcnt vmcnt(0)" ::: "memory");
  __syncthreads();

  // ---- issue lt chunk 0 (in flight during bsc setup) ----
  const short* lbase = ltb + (size_t)b * T1n * Dn;
  #pragma unroll
  for (int it = 0; it < 4; ++it)
    gl_lds16(lbase + soff[it], &lds_lt[0][it * 256 * 8 + wub]);

  // ---- B fragments scaled by k[m] once, kept in regs (64 VGPR) ----
  short8 bsc[2][8];
  {
    const float* kbase = kern + (size_t)m * Dn;
    #pragma unroll
    for (int kk = 0; kk < 8; ++kk) {
      int d8 = kk * 4 + hl;
      const f32x4* kp = reinterpret_cast<const f32x4*>(kbase + d8 * 8);
      f32x4 k0 = kp[0], k1 = kp[1];
      #pragma unroll
      for (int sub = 0; sub < 2; ++sub) {
        int brow = sub * 16 + bl;
        short8 r = *reinterpret_cast<const short8*>(&lds_rt[swz_chunk(brow, d8) * 8]);
        short8 v;
        v[0] = f2b(b2f(r[0]) * k0.x); v[1] = f2b(b2f(r[1]) * k0.y);
        v[2] = f2b(b2f(r[2]) * k0.z); v[3] = f2b(b2f(r[3]) * k0.w);
        v[4] = f2b(b2f(r[4]) * k1.x); v[5] = f2b(b2f(r[5]) * k1.y);
        v[6] = f2b(b2f(r[6]) * k1.z); v[7] = f2b(b2f(r[7]) * k1.w);
        bsc[sub][kk] = v;
      }
    }
  }

  float jmax0 = -1e30f, jmax1 = -1e30f;

  asm volatile("s_waitcnt vmcnt(0)" ::: "memory");
  __syncthreads();                          // lt chunk 0 ready

  // ---- 8 chunks of 32 i-rows, double-buffered ----
  for (int ic = 0; ic < 8; ++ic) {
    const int cur = ic & 1;
    if (ic < 7) {                           // prefetch next chunk
      #pragma unroll
      for (int it = 0; it < 4; ++it)
        gl_lds16(lbase + (ic + 1) * 32 * 256 + soff[it],
                 &lds_lt[cur ^ 1][it * 256 * 8 + wub]);
    }
    const short* lcur = lds_lt[cur];
    f32x4 a00 = {0.f,0.f,0.f,0.f}, a01 = {0.f,0.f,0.f,0.f};
    f32x4 a10 = {0.f,0.f,0.f,0.f}, a11 = {0.f,0.f,0.f,0.f};
    #pragma unroll
    for (int kk = 0; kk < 8; ++kk) {
      int d8 = kk * 4 + hl;
      short8 A0 = *reinterpret_cast<const short8*>(&lcur[swz_chunk(bl, d8) * 8]);
      short8 A1 = *reinterpret_cast<const short8*>(&lcur[swz_chunk(16 + bl, d8) * 8]);
      a00 = __builtin_amdgcn_mfma_f32_16x16x32_bf16(A0, bsc[0][kk], a00, 0, 0, 0);
      a01 = __builtin_amdgcn_mfma_f32_16x16x32_bf16(A0, bsc[1][kk], a01, 0, 0, 0);
      a10 = __builtin_amdgcn_mfma_f32_16x16x32_bf16(A1, bsc[0][kk], a10, 0, 0, 0);
      a11 = __builtin_amdgcn_mfma_f32_16x16x32_bf16(A1, bsc[1][kk], a11, 0, 0, 0);
    }
    jmax0 = fmaxf(jmax0, fmaxf(max4(a00), max4(a10)));
    jmax1 = fmaxf(jmax1, fmaxf(max4(a01), max4(a11)));
    if (ic < 7) {
      asm volatile("s_waitcnt vmcnt(0)" ::: "memory");
      __syncthreads();
    }
  }

  // ---- cross-lane col-max over the 4 row-groups, tanh, store ----
  jmax0 = fmaxf(jmax0, __shfl_xor(jmax0, 16));
  jmax0 = fmaxf(jmax0, __shfl_xor(jmax0, 32));
  jmax1 = fmaxf(jmax1, __shfl_xor(jmax1, 16));
  jmax1 = fmaxf(jmax1, __shfl_xor(jmax1, 32));
  if (hl < 2) {
    float v = hl ? jmax1 : jmax0;
    int j = j0 + hl * 16 + bl;
    out[((size_t)b * T2n + j) * MPn + m] = tanhf(v);
  }
}

extern "C" void kernel_launch(void* const* d_in, const int* in_sizes, int n_in,
                              void* d_out, int out_size, void* d_ws, size_t ws_size,
                              hipStream_t stream) {
  const float* lt   = (const float*)d_in[0];
  const float* rt   = (const float*)d_in[1];
  const float* kern = (const float*)d_in[2];
  float* out = (float*)d_out;

  short* ltb = (short*)d_ws;                       // 2 MB
  short* rtb = ltb + (size_t)Bn * T1n * Dn;        // 2 MB more

  cvt_bf16_kernel<<<1024, 256, 0, stream>>>(lt, rt, ltb, rtb);
  mp_match_kernel<<<1024, 256, 0, stream>>>(ltb, rtb, kern, out);
}